// Round 1
// 1052.869 us; speedup vs baseline: 1.0003x; 1.0003x over previous
//
#include <hip/hip_runtime.h>

// NearestNbrNegSampler: B=2048, D=256
// n[i][j][k]   = y[i][k] + (j==k ? 1 : 0) - (j-D==k ? 1 : 0),  j in [0,2D)
// nmsk[i][j]   = all_k( l[i][k] <= n[i][j][k] <= u[i][k] )
// Outputs concatenated flat: n (B*2D*D floats) then nmsk (B*2D floats 0/1).
//
// Streaming layout: block i owns row-batch i (512 KB of n). Each of the 4
// waves owns a CONTIGUOUS 128-row / 128 KB region (sequential 1 KB bursts,
// not 4 KB-strided). Perturbation structure: thread (wave jg, lane) touches
// exactly rows j = 4*lane + c (c = j&3) for the +1 half (waves 0-1) or
// j = 256 + 4*lane + c for the -1 half (waves 2-3). Within an unroll-by-4
// row group the perturbed component is fixed by j&3, so the whole group
// needs ONE compare (row-group index jr == lane2) + 4 predicated adds.
// Hot loop is essentially pure global_store_dwordx4.

#define BB 2048
#define DD 256

__global__ __launch_bounds__(256) void nnns_kernel(
    const float* __restrict__ l,
    const float* __restrict__ u,
    const float* __restrict__ y,
    float* __restrict__ n_out,
    float* __restrict__ m_out)
{
    const int i   = blockIdx.x;       // batch row
    const int tid = threadIdx.x;      // 256 threads

    // ---------------- mask part: thread tid == k ----------------
    __shared__ int s_fail;
    if (tid == 0) s_fail = 0;
    __syncthreads();

    const int k = tid;
    const float yv = y[i * DD + k];
    const float lv = l[i * DD + k];
    const float uv = u[i * DD + k];
    const bool ok = (lv <= yv) && (yv <= uv);
    if (!ok) atomicAdd(&s_fail, 1);   // compiler coalesces per-wave
    __syncthreads();
    const int fail = s_fail;

    // "all other k pass": no failures, or exactly one failure and it's me
    const bool others = (fail == 0) || (fail == 1 && !ok);
    const float yp = yv + 1.0f;
    const float ym = yv - 1.0f;
    const bool okp = (lv <= yp) && (yp <= uv);
    const bool okm = (lv <= ym) && (ym <= uv);
    m_out[(size_t)i * (2 * DD) + k]      = (others && okp) ? 1.0f : 0.0f;
    m_out[(size_t)i * (2 * DD) + DD + k] = (others && okm) ? 1.0f : 0.0f;

    // ---------------- n part: stream 512x256 tile ----------------
    const int lane = tid & 63;
    const int jg   = tid >> 6;        // wave id: rows [jg*128, jg*128+128)
    const int kb   = lane * 4;        // columns kb..kb+3 (float4)

    const float4 y4   = *(const float4*)(y + i * DD + kb);
    const float delta = (jg < 2) ? 1.0f : -1.0f;        // +1 half vs -1 half
    const int   lane2 = lane + ((jg >= 2) ? 64 : 0);    // matching row-group

    // wave-contiguous 128 KB region: rows jbase..jbase+127
    float4* p = (float4*)(n_out + (size_t)i * (2 * DD) * DD)
              + (size_t)(jg * 128) * (DD / 4);
    const int jr0 = jg * 32;          // row-group index of first group

    #pragma unroll 4
    for (int g = 0; g < 32; ++g) {    // 32 groups of 4 rows (4 KB each)
        const int jr = jr0 + g;       // wave-uniform row-group index
        float4 v0 = y4, v1 = y4, v2 = y4, v3 = y4;
        if (jr == lane2) {            // rare: one lane per matching group
            v0.x += delta;            // row 4*jr+0 perturbs component 0
            v1.y += delta;            // row 4*jr+1 perturbs component 1
            v2.z += delta;
            v3.w += delta;
        }
        p[lane]       = v0;
        p[64  + lane] = v1;
        p[128 + lane] = v2;
        p[192 + lane] = v3;
        p += 256;                     // next 4-row group (4 KB)
    }
}

extern "C" void kernel_launch(void* const* d_in, const int* in_sizes, int n_in,
                              void* d_out, int out_size, void* d_ws, size_t ws_size,
                              hipStream_t stream) {
    // setup_inputs order: a(0), b(1), c(2), l(3), u(4), h(5), y(6)
    const float* l = (const float*)d_in[3];
    const float* u = (const float*)d_in[4];
    const float* y = (const float*)d_in[6];

    float* n_out = (float*)d_out;                                   // B*2D*D
    float* m_out = (float*)d_out + (size_t)BB * (2 * DD) * DD;      // B*2D

    nnns_kernel<<<dim3(BB), dim3(256), 0, stream>>>(l, u, y, n_out, m_out);
}